// Round 3
// baseline (723.674 us; speedup 1.0000x reference)
//
#include <hip/hip_runtime.h>

#define SEQ   2048
#define BATCH 4096
#define HD    32

// ---------------- fast device math ----------------
__device__ __forceinline__ float exp2_fast(float a) {
#if __has_builtin(__builtin_amdgcn_exp2f)
    return __builtin_amdgcn_exp2f(a);
#else
    return exp2f(a);
#endif
}

__device__ __forceinline__ float rcp_fast(float a) {
#if __has_builtin(__builtin_amdgcn_rcpf)
    return __builtin_amdgcn_rcpf(a);
#else
    return 1.0f / a;
#endif
}

// tanh(x) = sign(x) * (1 - e^{-2|x|}) / (1 + e^{-2|x|})
__device__ __forceinline__ float fast_tanh(float v) {
    float ax = fabsf(v);
    float e  = exp2_fast(ax * -2.8853900817779268f);
    float r  = (1.0f - e) * rcp_fast(1.0f + e);
    return copysignf(r, v);
}

// DPP lane exchange (bit-exact xor patterns within 16-lane rows):
// 0xB1 quad_perm[1,0,3,2] = xor-1 ; 0x4E quad_perm[2,3,0,1] = xor-2
// 0x1B quad_perm[3,2,1,0] = xor-3 ; 0x141 row_half_mirror = xor-7
// 0x140 row_mirror = xor-15   (all verified on HW in rounds 0-2)
template <int CTRL>
__device__ __forceinline__ float dpp_x(float v) {
    return __int_as_float(
        __builtin_amdgcn_update_dpp(0, __float_as_int(v), CTRL, 0xF, 0xF, false));
}

// ds_swizzle xor-16 within each 32-lane group (verified r1/r2).
__device__ __forceinline__ float swz_xor16(float v) {
    return __int_as_float(__builtin_amdgcn_ds_swizzle(__float_as_int(v), 0x401F));
}

// 16-FMA accumulation over one k-half. Slot eo sources h_{i^eo} via DPP
// chains: h (eo 0-3), c7=h_{i^7} (eo 4-7), c8=h_{i^8} (eo 8-11),
// c15=h_{i^15} (eo 12-15). Weight W[eo] was loaded as column (L^eo) so
// every slot pairs the right h with the right weight.
#define ACC16(P0, P1, HS, C7, C8, C15, W)            \
    P0 = fmaf((HS),            W[0],  P0);           \
    P0 = fmaf(dpp_x<0xB1>(HS), W[1],  P0);           \
    P0 = fmaf(dpp_x<0x4E>(HS), W[2],  P0);           \
    P0 = fmaf(dpp_x<0x1B>(HS), W[3],  P0);           \
    P0 = fmaf(dpp_x<0x1B>(C7), W[4],  P0);           \
    P0 = fmaf(dpp_x<0x4E>(C7), W[5],  P0);           \
    P0 = fmaf(dpp_x<0xB1>(C7), W[6],  P0);           \
    P0 = fmaf((C7),            W[7],  P0);           \
    P1 = fmaf((C8),            W[8],  P1);           \
    P1 = fmaf(dpp_x<0xB1>(C8), W[9],  P1);           \
    P1 = fmaf(dpp_x<0x4E>(C8), W[10], P1);           \
    P1 = fmaf(dpp_x<0x1B>(C8), W[11], P1);           \
    P1 = fmaf(dpp_x<0x1B>(C15),W[12], P1);           \
    P1 = fmaf(dpp_x<0x4E>(C15),W[13], P1);           \
    P1 = fmaf(dpp_x<0xB1>(C15),W[14], P1);           \
    P1 = fmaf((C15),           W[15], P1);

// ---------------- kernel ----------------
// 32 lanes/element. Lane i: owns row i; k-half Hh = i>>4 covers k in
// [16*Hh, 16*Hh+16). Lane i accumulates rows i and i^16 over its k-half.
// h values for the k-half live exactly in the lane's own 16-lane DPP row
// (lane j holds h_j), so the per-step h all-gather is pure DPP — the LDS
// store->load round trip is GONE from the recurrence chain. The only
// cross-half op is one ds_swizzle of the partner-row partial, issued
// between the two FMA chains so its latency hides under FMA issue.
// Out-projection is pipelined one iteration so its swizzle never stalls.
__global__
__attribute__((amdgpu_flat_work_group_size(256, 256)))
__attribute__((amdgpu_waves_per_eu(2, 2)))
void rnn_elman_kernel(
    const float* __restrict__ x, const float* __restrict__ hidden,
    const float* __restrict__ W_ih, const float* __restrict__ b_ih,
    const float* __restrict__ W_hh, const float* __restrict__ b_hh,
    const float* __restrict__ W_fc, const float* __restrict__ b_fc,
    float* __restrict__ out)
{
    const int tid = threadIdx.x;
    const int i   = tid & 31;        // lane within element group == owned row
    const int L   = i & 15;          // position within DPP row
    const int Hh  = i >> 4;          // k-half index
    const int eb  = tid >> 5;        // element within block (0..7)
    const int e   = blockIdx.x * 8 + eb;
    const int rowA  = i;
    const int rowB  = i ^ 16;
    const int kbase = 16 * Hh;

    // ---- weights into registers, columns permuted to xor-gather order ----
    float wa[16], wb[16];
    #pragma unroll
    for (int eo = 0; eo < 16; ++eo) {
        const int kc = kbase + (L ^ eo);
        wa[eo] = W_hh[rowA * HD + kc];
        wb[eo] = W_hh[rowB * HD + kc];
    }
    const float wih  = W_ih[rowA];
    const float bias = b_ih[rowA] + b_hh[rowA];
    const float wfc  = W_fc[rowA];
    const float bfc  = b_fc[0];

    // ---- init: h_i lives in lane i; no LDS anywhere ----
    float h = hidden[e * HD + rowA];

    // ---- x prefetch pipe (distance 4) ----
    float xq0 = x[(size_t)0 * BATCH + e];
    float xq1 = x[(size_t)1 * BATCH + e];
    float xq2 = x[(size_t)2 * BATCH + e];
    float xq3 = x[(size_t)3 * BATCH + e];

    float u_keep = 0.f, u_swz = 0.f;   // pipelined out-projection state

    #pragma unroll 4
    for (int t = 0; t < SEQ; ++t) {
        // ---- pending output store from step t-1 (swizzle long completed) ----
        if (t > 0) {
            const float tot = u_keep + u_swz + bfc;
            if (i == 0) out[(size_t)(t - 1) * BATCH + e] = tot;
        }

        const float xv = xq0;
        xq0 = xq1; xq1 = xq2; xq2 = xq3;
        {
            int tt = t + 4; tt = tt < SEQ ? tt : SEQ - 1;   // uniform clamp
            xq3 = x[(size_t)tt * BATCH + e];
        }

        // ---- gather companions: h_{i^7}, h_{i^15}, h_{i^8} ----
        const float c7  = dpp_x<0x141>(h);
        const float c15 = dpp_x<0x140>(h);
        const float c8  = dpp_x<0x141>(c15);   // (i^15)^7 = i^8

        // ---- partner-row chain first, then swizzle, then own-row chain ----
        float b0 = 0.f, b1 = 0.f;              // row i^16, no seed (partner seeds it)
        ACC16(b0, b1, h, c7, c8, c15, wb);
        const float pb   = b0 + b1;
        const float recv = swz_xor16(pb);      // issued now, consumed after A-chain

        float a0 = fmaf(xv, wih, bias);        // row i seed rides in a0
        float a1 = 0.f;
        ACC16(a0, a1, h, c7, c8, c15, wa);

        const float z = (a0 + a1) + recv;      // partner's half of row i arrives
        h = fast_tanh(z);

        // ---- out projection, fully pipelined (finalized next iteration) ----
        float u = h * wfc;
        u += dpp_x<0xB1>(u);    // xor-1
        u += dpp_x<0x4E>(u);    // xor-2
        u += dpp_x<0x141>(u);   // == xor-4 on quad-uniform sums
        u += dpp_x<0x140>(u);   // == xor-8 on 8-uniform sums -> 16-half total
        u_keep = u;
        u_swz  = swz_xor16(u);  // other half's total, consumed at t+1
    }

    // ---- flush final output (t = SEQ-1) ----
    {
        const float tot = u_keep + u_swz + bfc;
        if (i == 0) out[(size_t)(SEQ - 1) * BATCH + e] = tot;
    }
}

// ---------------- launch ----------------
extern "C" void kernel_launch(void* const* d_in, const int* in_sizes, int n_in,
                              void* d_out, int out_size, void* d_ws, size_t ws_size,
                              hipStream_t stream) {
    const float* x    = (const float*)d_in[0];
    const float* hid  = (const float*)d_in[1];
    const float* W_ih = (const float*)d_in[2];
    const float* b_ih = (const float*)d_in[3];
    const float* W_hh = (const float*)d_in[4];
    const float* b_hh = (const float*)d_in[5];
    const float* W_fc = (const float*)d_in[6];
    const float* b_fc = (const float*)d_in[7];
    float* out = (float*)d_out;

    dim3 grid(BATCH / 8);    // 512 blocks -> 2 blocks/CU
    dim3 block(256);         // 8 elements/block; 8 waves/CU, 2/SIMD
    rnn_elman_kernel<<<grid, block, 0, stream>>>(x, hid, W_ih, b_ih, W_hh, b_hh,
                                                 W_fc, b_fc, out);
}